// Round 2
// baseline (186.812 us; speedup 1.0000x reference)
//
#include <hip/hip_runtime.h>

#define B_  2
#define TQ  1024
#define TV  1024
#define DD  512
#define UU  128

#define CM  32
#define CN  64
#define CKT 64

// ---------------- prep: scale2[u] = -2*scale[u] ----------------
__global__ void prep_scale(const float* __restrict__ scale, float* __restrict__ scale2){
    int u = threadIdx.x;
    if (u < UU) scale2[u] = -2.0f * scale[u];
}

// ---------------- projections: q2 = C*query@W1, k2 = C*value@W2 (C = 2*log2(e)) ----
__global__ __launch_bounds__(256)
void proj_kernel(const float* __restrict__ query, const float* __restrict__ value,
                 const float* __restrict__ W1,    const float* __restrict__ W2,
                 float* __restrict__ q2, float* __restrict__ k2){
    const float TWO_LOG2E = 2.8853900817779268f;
    const float* X = blockIdx.z ? value : query;
    const float* W = blockIdx.z ? W2    : W1;
    float* out     = blockIdx.z ? k2    : q2;

    const int u    = threadIdx.x & 127;
    const int half = threadIdx.x >> 7;
    const int b    = blockIdx.y;
    const int t0   = blockIdx.x * 8 + half * 4;
    const float* x = X + ((size_t)b * TQ + t0) * DD;

    float acc0 = 0.f, acc1 = 0.f, acc2 = 0.f, acc3 = 0.f;
    for (int d = 0; d < DD; d += 4){
        float w0 = W[(d+0)*UU + u];
        float w1 = W[(d+1)*UU + u];
        float w2 = W[(d+2)*UU + u];
        float w3 = W[(d+3)*UU + u];
        float4 x0 = *reinterpret_cast<const float4*>(x + 0*DD + d);
        float4 x1 = *reinterpret_cast<const float4*>(x + 1*DD + d);
        float4 x2 = *reinterpret_cast<const float4*>(x + 2*DD + d);
        float4 x3 = *reinterpret_cast<const float4*>(x + 3*DD + d);
        acc0 = fmaf(x0.x,w0,acc0); acc0 = fmaf(x0.y,w1,acc0); acc0 = fmaf(x0.z,w2,acc0); acc0 = fmaf(x0.w,w3,acc0);
        acc1 = fmaf(x1.x,w0,acc1); acc1 = fmaf(x1.y,w1,acc1); acc1 = fmaf(x1.z,w2,acc1); acc1 = fmaf(x1.w,w3,acc1);
        acc2 = fmaf(x2.x,w0,acc2); acc2 = fmaf(x2.y,w1,acc2); acc2 = fmaf(x2.z,w2,acc2); acc2 = fmaf(x2.w,w3,acc2);
        acc3 = fmaf(x3.x,w0,acc3); acc3 = fmaf(x3.y,w1,acc3); acc3 = fmaf(x3.z,w2,acc3); acc3 = fmaf(x3.w,w3,acc3);
    }
    size_t o = ((size_t)b * TQ + t0) * UU + u;
    out[o + 0*UU] = TWO_LOG2E * acc0;
    out[o + 1*UU] = TWO_LOG2E * acc1;
    out[o + 2*UU] = TWO_LOG2E * acc2;
    out[o + 3*UU] = TWO_LOG2E * acc3;
}

// ---------------- fused scores + softmax ----------------
// scores[b,q,k] = sum_u scale2[u] * rcp(1 + exp2(q2[b,q,u] + k2[b,k,u]))   (+const, cancels in softmax)
// one wave per q-row; k2 tile [64 k][128 u] in LDS, float4-XOR-swizzled rows
__global__ __launch_bounds__(256)
void attn_kernel(const float* __restrict__ q2, const float* __restrict__ k2,
                 const float* __restrict__ scale2,
                 float* __restrict__ attn /*[B][TQ][TV] fp32*/){
    __shared__ float4 kt4[64 * 32];      // 32 KB, [k][u4] swizzled
    __shared__ float  qs[4][UU];
    __shared__ float  sc[UU];

    const float LOG2E = 1.4426950408889634f;
    const int b    = blockIdx.y;
    const int q0   = blockIdx.x * 4;
    const int tid  = threadIdx.x;
    const int wave = tid >> 6, lane = tid & 63;

    for (int i = tid; i < 4*UU + UU; i += 256){
        if (i < 4*UU) qs[i >> 7][i & 127] = q2[((size_t)b * TQ + q0 + (i >> 7)) * UU + (i & 127)];
        else          sc[i - 4*UU] = scale2[i - 4*UU];
    }

    const float4* k2v = reinterpret_cast<const float4*>(k2 + (size_t)b * TV * UU);
    const float4* qs4 = reinterpret_cast<const float4*>(&qs[wave][0]);
    const float4* sc4 = reinterpret_cast<const float4*>(&sc[0]);

    float s[16];
    for (int t = 0; t < 16; ++t){
        __syncthreads();
        #pragma unroll
        for (int i = 0; i < 8; ++i){
            int idx = tid + 256*i;                 // 0..2047
            int kk  = idx >> 5, u4 = idx & 31;
            kt4[(kk << 5) | (u4 ^ (kk & 31))] = k2v[(size_t)(t*64 + kk) * 32 + u4];
        }
        __syncthreads();

        float a0 = 0.f, a1 = 0.f, a2 = 0.f, a3 = 0.f;
        const int lbase = lane << 5, lm = lane & 31;
        #pragma unroll
        for (int j = 0; j < 32; ++j){
            float4 kv = kt4[lbase | (j ^ lm)];
            float4 q4 = qs4[j];
            float4 s4 = sc4[j];
            a0 = fmaf(s4.x, __builtin_amdgcn_rcpf(1.0f + __builtin_amdgcn_exp2f(q4.x + kv.x)), a0);
            a1 = fmaf(s4.y, __builtin_amdgcn_rcpf(1.0f + __builtin_amdgcn_exp2f(q4.y + kv.y)), a1);
            a2 = fmaf(s4.z, __builtin_amdgcn_rcpf(1.0f + __builtin_amdgcn_exp2f(q4.z + kv.z)), a2);
            a3 = fmaf(s4.w, __builtin_amdgcn_rcpf(1.0f + __builtin_amdgcn_exp2f(q4.w + kv.w)), a3);
        }
        s[t] = (a0 + a1) + (a2 + a3);
    }

    // softmax across the 1024 k (lane holds k = t*64 + lane)
    float m = s[0];
    #pragma unroll
    for (int t = 1; t < 16; ++t) m = fmaxf(m, s[t]);
    #pragma unroll
    for (int off = 32; off >= 1; off >>= 1) m = fmaxf(m, __shfl_xor(m, off, 64));
    float sum = 0.f;
    #pragma unroll
    for (int t = 0; t < 16; ++t){ s[t] = __builtin_amdgcn_exp2f((s[t] - m) * LOG2E); sum += s[t]; }
    #pragma unroll
    for (int off = 32; off >= 1; off >>= 1) sum += __shfl_xor(sum, off, 64);
    float inv = 1.0f / sum;

    float* arow = attn + ((size_t)b * TQ + q0 + wave) * TV;
    #pragma unroll
    for (int t = 0; t < 16; ++t) arow[t*64 + lane] = s[t] * inv;
}

// ---------------- context = attn @ value (all fp32) ----------------
__global__ __launch_bounds__(256)
void ctx_kernel(const float* __restrict__ attn, const float* __restrict__ value,
                float* __restrict__ ctx){
    __shared__ float As[CM][CKT + 4];   // [m][k], row stride 68 floats (16B-aligned)
    __shared__ float Vs[CKT][CN];       // [k][n]

    const int b  = blockIdx.z;
    const int m0 = blockIdx.x * CM;
    const int n0 = blockIdx.y * CN;
    const int tid = threadIdx.x;
    const int tx = tid & 15, ty = tid >> 4;

    const float* abase = attn + ((size_t)b * TQ + m0) * TV;
    const float* vbase = value + (size_t)b * TV * DD;

    float acc[2][4] = {};
    for (int kt = 0; kt < TV; kt += CKT){
        __syncthreads();
        #pragma unroll
        for (int i = 0; i < 2; ++i){
            int id = tid + 256*i;               // 0..511
            int row = id >> 4, c4 = id & 15;
            *reinterpret_cast<float4*>(&As[row][c4*4]) =
                *reinterpret_cast<const float4*>(abase + (size_t)row * TV + kt + c4*4);
        }
        #pragma unroll
        for (int i = 0; i < 4; ++i){
            int id = tid + 256*i;               // 0..1023
            int row = id >> 4, c4 = id & 15;
            *reinterpret_cast<float4*>(&Vs[row][c4*4]) =
                *reinterpret_cast<const float4*>(vbase + (size_t)(kt + row) * DD + n0 + c4*4);
        }
        __syncthreads();
        #pragma unroll
        for (int k = 0; k < CKT; ++k){
            float a0 = As[ty*2+0][k];
            float a1 = As[ty*2+1][k];
            float4 b4 = *reinterpret_cast<const float4*>(&Vs[k][tx*4]);
            acc[0][0] = fmaf(a0, b4.x, acc[0][0]);
            acc[0][1] = fmaf(a0, b4.y, acc[0][1]);
            acc[0][2] = fmaf(a0, b4.z, acc[0][2]);
            acc[0][3] = fmaf(a0, b4.w, acc[0][3]);
            acc[1][0] = fmaf(a1, b4.x, acc[1][0]);
            acc[1][1] = fmaf(a1, b4.y, acc[1][1]);
            acc[1][2] = fmaf(a1, b4.z, acc[1][2]);
            acc[1][3] = fmaf(a1, b4.w, acc[1][3]);
        }
    }
    #pragma unroll
    for (int i = 0; i < 2; ++i){
        float4 o;
        o.x = acc[i][0]; o.y = acc[i][1]; o.z = acc[i][2]; o.w = acc[i][3];
        *reinterpret_cast<float4*>(ctx + ((size_t)b * TQ + m0 + ty*2 + i) * DD + n0 + tx*4) = o;
    }
}

extern "C" void kernel_launch(void* const* d_in, const int* in_sizes, int n_in,
                              void* d_out, int out_size, void* d_ws, size_t ws_size,
                              hipStream_t stream){
    const float* query = (const float*)d_in[0];
    const float* value = (const float*)d_in[1];
    const float* W1    = (const float*)d_in[2];
    const float* W2    = (const float*)d_in[3];
    const float* scale = (const float*)d_in[4];

    float* q2     = (float*)d_ws;                         // B*TQ*UU floats (1 MB)
    float* k2     = q2 + (size_t)B_ * TQ * UU;            // B*TV*UU floats (1 MB)
    float* scale2 = k2 + (size_t)B_ * TV * UU;            // 128 floats

    float* out  = (float*)d_out;
    float* ctx  = out;                                     // [B][TQ][DD]
    float* attn = out + (size_t)B_ * TQ * DD;              // [B][TQ][TV]

    prep_scale<<<1, 128, 0, stream>>>(scale, scale2);
    proj_kernel<<<dim3(TQ/8, B_, 2), 256, 0, stream>>>(query, value, W1, W2, q2, k2);
    attn_kernel<<<dim3(TQ/4, B_), 256, 0, stream>>>(q2, k2, scale2, attn);
    ctx_kernel<<<dim3(TQ/CM, DD/CN, B_), 256, 0, stream>>>(attn, value, ctx);
}